// Round 7
// baseline (188.303 us; speedup 1.0000x reference)
//
#include <hip/hip_runtime.h>
#include <hip/hip_bf16.h>
#include <math.h>

#define NB 4096     // batch
#define NN 8192     // N = B * n_views
#define DD 128      // feature dim
#define NSPLIT 16   // j-splits; 512 cols per block
#define NRB 64      // row-blocks of 128 rows

constexpr float INV_T = 14.285714285714286f;   // 1/0.07 (= subtracted row max M)
constexpr float EC1   = 20.609929155556620f;   // INV_T * log2(e)
constexpr float EC0   = -20.609929155556620f;  // -INV_T * log2(e)
constexpr float LN2   = 0.6931471805599453f;

typedef __attribute__((ext_vector_type(8))) short bf16x8;
typedef __attribute__((ext_vector_type(4))) float f32x4;

__device__ __forceinline__ float bf2f(ushort u) {
    union { unsigned int i; float f; } v; v.i = ((unsigned int)u) << 16; return v.f;
}

// ---- kernel 1: L2-normalize rows -> bf16 + selfdot; zero accumulators ----
__global__ __launch_bounds__(256) void k_norm(const float* __restrict__ feat,
                                              ushort* __restrict__ fb,
                                              float* __restrict__ selfdot,
                                              float* __restrict__ zbase,  // g_se,g_ps,g_ct,cnt
                                              float* __restrict__ out) {
    const int gid = blockIdx.x * 256 + threadIdx.x;
    if (gid < 3 * NN + NRB) zbase[gid] = 0.0f;  // bit-zero == int 0 for cnt
    if (gid == 0) out[0] = 0.0f;

    const int r    = gid >> 6;                  // one wave per row
    const int lane = threadIdx.x & 63;
    const float2 v = ((const float2*)(feat + (size_t)r * DD))[lane];
    float ss = v.x * v.x + v.y * v.y;
#pragma unroll
    for (int off = 1; off < 64; off <<= 1) ss += __shfl_xor(ss, off, 64);
    const float scale = 1.0f / fmaxf(sqrtf(ss), 1e-12f);
    __hip_bfloat162 h2;
    h2.x = __float2bfloat16(v.x * scale);
    h2.y = __float2bfloat16(v.y * scale);
    ((__hip_bfloat162*)(fb + (size_t)r * DD))[lane] = h2;
    // self-dot of the QUANTIZED row (matches the MFMA diagonal)
    const float xb = bf2f(((ushort2*)&h2)->x), yb = bf2f(((ushort2*)&h2)->y);
    float s2 = xb * xb + yb * yb;
#pragma unroll
    for (int off = 1; off < 64; off <<= 1) s2 += __shfl_xor(s2, off, 64);
    if (lane == 0) selfdot[r] = s2;
}

// ---- kernel 2: barrier-free F*F^T + fused epilogue + last-block finalize ----
// Block: 128 rows x 512 cols; 4 waves of 32 rows. All 4 waves stream the SAME
// B-fragment addresses (register double-buffered) -> 3/4 L1 hits, no LDS, no
// __syncthreads in the hot loop, waves fully independent.
// Grid 1024 = 64 rb x 16 js -> 4 blocks/CU, 16 waves/CU.
__global__ __launch_bounds__(256, 4) void k_main(const ushort* __restrict__ fb,
                                                 const int* __restrict__ labels,
                                                 const float* __restrict__ selfdot,
                                                 float* __restrict__ g_se,
                                                 float* __restrict__ g_ps,
                                                 float* __restrict__ g_ct,
                                                 int* __restrict__ cnt,
                                                 float* __restrict__ out) {
    __shared__ int slab[512];     // labels of this block's col range (tiny, one-time)
    __shared__ int lastflag;
    __shared__ float sred[4];

    const int tid  = threadIdx.x;
    const int lane = tid & 63;
    const int w    = tid >> 6;
    const int rb   = blockIdx.x >> 4;            // 0..63
    const int js   = blockIdx.x & (NSPLIT - 1);  // 0..15
    const int i0   = rb * 128 + w * 32;
    const int j0   = js * 512;
    const int q    = lane >> 4;
    const int n15  = lane & 15;

    slab[tid]       = labels[(j0 + tid) & (NB - 1)];
    slab[tid + 256] = labels[(j0 + tid + 256) & (NB - 1)];
    __syncthreads();   // one-time; hot loop below is barrier-free

    // A fragments: 2 row-tiles x 4 kt (32 regs), resident whole kernel
    bf16x8 afrag[2][4];
#pragma unroll
    for (int tt = 0; tt < 2; ++tt) {
        const ushort* rp = fb + (size_t)(i0 + tt * 16 + n15) * DD + q * 8;
#pragma unroll
        for (int kt = 0; kt < 4; ++kt) afrag[tt][kt] = *(const bf16x8*)(rp + kt * 32);
    }
    // labels of this lane's 8 accumulator rows (C/D map: row = q*4+r)
    int labi[8];
#pragma unroll
    for (int tt = 0; tt < 2; ++tt)
#pragma unroll
        for (int r = 0; r < 4; ++r)
            labi[tt * 4 + r] = labels[(i0 + tt * 16 + q * 4 + r) & (NB - 1)];

    float a_se[8] = {}, a_ps[8] = {}, a_ct[8] = {};

    bf16x8 cur[4], nxt[4];
    {
        const ushort* bp = fb + (size_t)(j0 + n15) * DD + q * 8;
#pragma unroll
        for (int kt = 0; kt < 4; ++kt) cur[kt] = *(const bf16x8*)(bp + kt * 32);
    }

    for (int jt = 0; jt < 32; ++jt) {
        // prefetch next 16-col tile (wraps on last iter; harmless)
        const ushort* bpn = fb + (size_t)(j0 + (((jt + 1) & 31) << 4) + n15) * DD + q * 8;
#pragma unroll
        for (int kt = 0; kt < 4; ++kt) nxt[kt] = *(const bf16x8*)(bpn + kt * 32);

        const int labj = slab[jt * 16 + n15];
        f32x4 a0 = {0.f, 0.f, 0.f, 0.f}, a1 = {0.f, 0.f, 0.f, 0.f};
#pragma unroll
        for (int kt = 0; kt < 4; ++kt) {
            a0 = __builtin_amdgcn_mfma_f32_16x16x32_bf16(afrag[0][kt], cur[kt], a0, 0, 0, 0);
            a1 = __builtin_amdgcn_mfma_f32_16x16x32_bf16(afrag[1][kt], cur[kt], a1, 0, 0, 0);
        }
#pragma unroll
        for (int r = 0; r < 4; ++r) {
            const float d0 = a0[r], d1 = a1[r];
            a_se[r]     += __builtin_amdgcn_exp2f(fmaf(d0, EC1, EC0));
            a_se[4 + r] += __builtin_amdgcn_exp2f(fmaf(d1, EC1, EC0));
            const float m0 = (labi[r] == labj) ? 1.0f : 0.0f;
            const float m1 = (labi[4 + r] == labj) ? 1.0f : 0.0f;
            a_ps[r]     = fmaf(m0, d0, a_ps[r]);     // raw dot; scaled in finalize
            a_ps[4 + r] = fmaf(m1, d1, a_ps[4 + r]);
            a_ct[r]     += m0;
            a_ct[4 + r] += m1;
        }
#pragma unroll
        for (int kt = 0; kt < 4; ++kt) cur[kt] = nxt[kt];
    }

    // quad-reduce (16 lanes share rows), one atomicAdd per row per value
#pragma unroll
    for (int s = 0; s < 8; ++s) {
        float v1 = a_se[s], v2 = a_ps[s], v3 = a_ct[s];
#pragma unroll
        for (int off = 1; off < 16; off <<= 1) {
            v1 += __shfl_xor(v1, off, 64);
            v2 += __shfl_xor(v2, off, 64);
            v3 += __shfl_xor(v3, off, 64);
        }
        if (n15 == 0) {
            const int row = i0 + (s >> 2) * 16 + q * 4 + (s & 3);
            atomicAdd(&g_se[row], v1);
            atomicAdd(&g_ps[row], v2);
            atomicAdd(&g_ct[row], v3);
        }
    }

    // ---- last-block-per-rb finalize (no spin; cannot deadlock) ----
    __syncthreads();
    __threadfence();
    if (tid == 0) lastflag = (atomicAdd(&cnt[rb], 1) == NSPLIT - 1);
    __syncthreads();
    if (lastflag) {
        __threadfence();
        float v = 0.0f;
        if (tid < 128) {
            const int r = rb * 128 + tid;
            const float se0 = g_se[r], ps = g_ps[r], ct0 = g_ct[r];
            const float sd  = selfdot[r];
            const float se  = se0 - __builtin_amdgcn_exp2f(fmaf(sd, EC1, EC0));
            const float ct  = ct0 - 1.0f;
            const float possum = INV_T * (ps - sd - ct);
            const float lg  = __builtin_amdgcn_logf(se + 1e-12f) * LN2;
            const float mlpp = (possum - ct * lg) / fmaxf(ct, 1.0f);
            v = -mlpp * (1.0f / (float)NN);
        }
#pragma unroll
        for (int off = 1; off < 64; off <<= 1) v += __shfl_xor(v, off, 64);
        if (lane == 0) sred[w] = v;
        __syncthreads();
        if (tid == 0) atomicAdd(out, sred[0] + sred[1] + sred[2] + sred[3]);
    }
}

extern "C" void kernel_launch(void* const* d_in, const int* in_sizes, int n_in,
                              void* d_out, int out_size, void* d_ws, size_t ws_size,
                              hipStream_t stream) {
    const float* feat = (const float*)d_in[0];
    const int* labels = (const int*)d_in[1];
    float* out        = (float*)d_out;
    char* ws          = (char*)d_ws;

    ushort* fb      = (ushort*)ws;                                   // 2 MB
    float* selfdot  = (float*)(ws + (size_t)2 * 1024 * 1024);        // NN f32
    float* g_se     = selfdot + NN;                                  // NN f32 (zbase starts here)
    float* g_ps     = g_se + NN;
    float* g_ct     = g_ps + NN;
    int*   cnt      = (int*)(g_ct + NN);                             // NRB i32

    k_norm<<<NN / 4, 256, 0, stream>>>(feat, fb, selfdot, g_se, out);
    k_main<<<NRB * NSPLIT, 256, 0, stream>>>(fb, labels, selfdot, g_se, g_ps, g_ct, cnt, out);
}

// Round 8
// 156.030 us; speedup vs baseline: 1.2068x; 1.2068x over previous
//
#include <hip/hip_runtime.h>
#include <hip/hip_bf16.h>
#include <math.h>

#define NB 4096     // batch
#define NN 8192     // N = B * n_views
#define DD 128      // feature dim
#define NSPLIT 16   // j-splits; 512 cols per block
#define CHUNK 64    // cols per LDS-staged chunk
#define NCHUNK 8    // 512 / 64
#define NRB 64      // row-blocks of 128 rows

constexpr float INV_T = 14.285714285714286f;   // 1/0.07 (= subtracted row max M)
constexpr float EC1   = 20.609929155556620f;   // INV_T * log2(e)
constexpr float EC0   = -20.609929155556620f;  // -INV_T * log2(e)
constexpr float LN2   = 0.6931471805599453f;

typedef __attribute__((ext_vector_type(8))) short bf16x8;
typedef __attribute__((ext_vector_type(4))) float f32x4;

__device__ __forceinline__ float bf2f(ushort u) {
    union { unsigned int i; float f; } v; v.i = ((unsigned int)u) << 16; return v.f;
}

// ---- kernel 1: L2-normalize rows -> bf16 + selfdot; zero accumulators ----
__global__ __launch_bounds__(256) void k_norm(const float* __restrict__ feat,
                                              ushort* __restrict__ fb,
                                              float* __restrict__ selfdot,
                                              float* __restrict__ zbase,  // g_se,g_ps,g_ct,cnt
                                              float* __restrict__ out) {
    const int gid = blockIdx.x * 256 + threadIdx.x;
    if (gid < 3 * NN + NRB) zbase[gid] = 0.0f;  // bit-zero == int 0 for cnt
    if (gid == 0) out[0] = 0.0f;

    const int r    = gid >> 6;                  // one wave per row
    const int lane = threadIdx.x & 63;
    const float2 v = ((const float2*)(feat + (size_t)r * DD))[lane];
    float ss = v.x * v.x + v.y * v.y;
#pragma unroll
    for (int off = 1; off < 64; off <<= 1) ss += __shfl_xor(ss, off, 64);
    const float scale = 1.0f / fmaxf(sqrtf(ss), 1e-12f);
    __hip_bfloat162 h2;
    h2.x = __float2bfloat16(v.x * scale);
    h2.y = __float2bfloat16(v.y * scale);
    ((__hip_bfloat162*)(fb + (size_t)r * DD))[lane] = h2;
    // self-dot of the QUANTIZED row (matches the MFMA diagonal)
    const float xb = bf2f(((ushort2*)&h2)->x), yb = bf2f(((ushort2*)&h2)->y);
    float s2 = xb * xb + yb * yb;
#pragma unroll
    for (int off = 1; off < 64; off <<= 1) s2 += __shfl_xor(s2, off, 64);
    if (lane == 0) selfdot[r] = s2;
}

// stage one 64-col chunk's B-fragments into LDS, fragment-major.
// Wave w stages j-tile jt=w (4 kt instrs). LDS dst = wave-uniform base +
// lane*16 (HW rule); the per-lane GLOBAL address does the fragment gather.
__device__ __forceinline__ void stage_chunk(const ushort* __restrict__ fb, ushort* sbuf,
                                            int jb, int w, int n15, int q) {
    const ushort* g = fb + (size_t)(jb + w * 16 + n15) * DD + q * 8;
#pragma unroll
    for (int kt = 0; kt < 4; ++kt)
        __builtin_amdgcn_global_load_lds(
            (const __attribute__((address_space(1))) void*)(g + kt * 32),
            (__attribute__((address_space(3))) void*)(sbuf + (w * 4 + kt) * 512),
            16, 0, 0);
}

// ---- kernel 2: F*F^T, LDS double-buffered B (R5 hot loop verbatim),
//      fused exp/pos/cnt epilogue + atomic row-merge + last-block finalize ----
// Block: 128 rows x 512 cols; 4 waves of 32 rows. Grid 1024 = 64 rb x 16 js.
__global__ __launch_bounds__(256, 4) void k_main(const ushort* __restrict__ fb,
                                                 const int* __restrict__ labels,
                                                 const float* __restrict__ selfdot,
                                                 float* __restrict__ g_se,
                                                 float* __restrict__ g_ps,
                                                 float* __restrict__ g_ct,
                                                 int* __restrict__ cnt,
                                                 float* __restrict__ out) {
    __shared__ ushort sB[2][CHUNK * DD];   // 2 x 16 KB, fragment-major
    __shared__ int slab[512];              // labels of this block's col range
    __shared__ int lastflag;
    __shared__ float sred[4];

    const int tid  = threadIdx.x;
    const int lane = tid & 63;
    const int w    = tid >> 6;
    const int rb   = blockIdx.x >> 4;           // 0..63 row-block
    const int js   = blockIdx.x & (NSPLIT - 1); // 0..15
    const int i0   = rb * 128 + w * 32;
    const int jb0  = js * 512;
    const int q    = lane >> 4;
    const int n15  = lane & 15;

    slab[tid]       = labels[(jb0 + tid) & (NB - 1)];
    slab[tid + 256] = labels[(jb0 + tid + 256) & (NB - 1)];

    // A fragments: 2 row-tiles x 4 kt (32 regs), resident whole kernel
    bf16x8 afrag[2][4];
#pragma unroll
    for (int tt = 0; tt < 2; ++tt) {
        const ushort* rp = fb + (size_t)(i0 + tt * 16 + n15) * DD + q * 8;
#pragma unroll
        for (int kt = 0; kt < 4; ++kt) afrag[tt][kt] = *(const bf16x8*)(rp + kt * 32);
    }
    // labels of this lane's 8 accumulator rows (C/D map: row = q*4+r)
    int labi[8];
#pragma unroll
    for (int tt = 0; tt < 2; ++tt)
#pragma unroll
        for (int r = 0; r < 4; ++r)
            labi[tt * 4 + r] = labels[(i0 + tt * 16 + q * 4 + r) & (NB - 1)];

    float a_se[8] = {}, a_ps[8] = {}, a_ct[8] = {};

    stage_chunk(fb, &sB[0][0], jb0, w, n15, q);
    __syncthreads();

    for (int c = 0; c < NCHUNK; ++c) {
        if (c + 1 < NCHUNK)
            stage_chunk(fb, &sB[(c + 1) & 1][0], jb0 + (c + 1) * CHUNK, w, n15, q);
        const ushort* sb = &sB[c & 1][0];
        const int crel = c * CHUNK;
#pragma unroll
        for (int jt = 0; jt < 4; ++jt) {
            bf16x8 bf[4];
#pragma unroll
            for (int kt = 0; kt < 4; ++kt)
                bf[kt] = *(const bf16x8*)(sb + (jt * 4 + kt) * 512 + lane * 8); // conflict-free
            const int labj = slab[crel + jt * 16 + n15];
            f32x4 a0 = {0.f, 0.f, 0.f, 0.f}, a1 = {0.f, 0.f, 0.f, 0.f};
#pragma unroll
            for (int kt = 0; kt < 4; ++kt) {
                a0 = __builtin_amdgcn_mfma_f32_16x16x32_bf16(afrag[0][kt], bf[kt], a0, 0, 0, 0);
                a1 = __builtin_amdgcn_mfma_f32_16x16x32_bf16(afrag[1][kt], bf[kt], a1, 0, 0, 0);
            }
#pragma unroll
            for (int r = 0; r < 4; ++r) {
                const float d0 = a0[r], d1 = a1[r];
                a_se[r]     += __builtin_amdgcn_exp2f(fmaf(d0, EC1, EC0));
                a_se[4 + r] += __builtin_amdgcn_exp2f(fmaf(d1, EC1, EC0));
                const bool m0 = (labi[r] == labj), m1 = (labi[4 + r] == labj);
                a_ps[r]     += m0 ? d0 : 0.0f;   // raw dot; scaled/shifted in finalize
                a_ps[4 + r] += m1 ? d1 : 0.0f;
                a_ct[r]     += m0 ? 1.0f : 0.0f;
                a_ct[4 + r] += m1 ? 1.0f : 0.0f;
            }
        }
        __syncthreads();
    }

    // quad-reduce (16 lanes share rows), one atomicAdd per row per value
#pragma unroll
    for (int s = 0; s < 8; ++s) {
        float v1 = a_se[s], v2 = a_ps[s], v3 = a_ct[s];
#pragma unroll
        for (int off = 1; off < 16; off <<= 1) {
            v1 += __shfl_xor(v1, off, 64);
            v2 += __shfl_xor(v2, off, 64);
            v3 += __shfl_xor(v3, off, 64);
        }
        if (n15 == 0) {
            const int row = i0 + (s >> 2) * 16 + q * 4 + (s & 3);
            atomicAdd(&g_se[row], v1);
            atomicAdd(&g_ps[row], v2);
            atomicAdd(&g_ct[row], v3);
        }
    }

    // ---- last-block-per-rb finalize (no spin; cannot deadlock) ----
    __syncthreads();
    __threadfence();
    if (tid == 0) lastflag = (atomicAdd(&cnt[rb], 1) == NSPLIT - 1);
    __syncthreads();
    if (lastflag) {
        __threadfence();
        float v = 0.0f;
        if (tid < 128) {
            const int r = rb * 128 + tid;
            const float se0 = g_se[r], ps = g_ps[r], ct0 = g_ct[r];
            const float sd  = selfdot[r];
            const float se  = se0 - __builtin_amdgcn_exp2f(fmaf(sd, EC1, EC0));
            const float ct  = ct0 - 1.0f;
            const float possum = INV_T * (ps - sd - ct);
            const float lg  = __builtin_amdgcn_logf(se + 1e-12f) * LN2;
            const float mlpp = (possum - ct * lg) / fmaxf(ct, 1.0f);
            v = -mlpp * (1.0f / (float)NN);
        }
#pragma unroll
        for (int off = 1; off < 64; off <<= 1) v += __shfl_xor(v, off, 64);
        if (lane == 0) sred[w] = v;
        __syncthreads();
        if (tid == 0) atomicAdd(out, sred[0] + sred[1] + sred[2] + sred[3]);
    }
}

extern "C" void kernel_launch(void* const* d_in, const int* in_sizes, int n_in,
                              void* d_out, int out_size, void* d_ws, size_t ws_size,
                              hipStream_t stream) {
    const float* feat = (const float*)d_in[0];
    const int* labels = (const int*)d_in[1];
    float* out        = (float*)d_out;
    char* ws          = (char*)d_ws;

    ushort* fb      = (ushort*)ws;                                   // 2 MB
    float* selfdot  = (float*)(ws + (size_t)2 * 1024 * 1024);        // NN f32
    float* g_se     = selfdot + NN;                                  // zbase starts here
    float* g_ps     = g_se + NN;
    float* g_ct     = g_ps + NN;
    int*   cnt      = (int*)(g_ct + NN);                             // NRB i32

    k_norm<<<NN / 4, 256, 0, stream>>>(feat, fb, selfdot, g_se, out);
    k_main<<<NRB * NSPLIT, 256, 0, stream>>>(fb, labels, selfdot, g_se, g_ps, g_ct, cnt, out);
}

// Round 9
// 95.299 us; speedup vs baseline: 1.9759x; 1.6373x over previous
//
#include <hip/hip_runtime.h>
#include <hip/hip_bf16.h>
#include <math.h>

#define NB 4096     // batch
#define NN 8192     // N = B * n_views
#define DD 128      // feature dim
#define NSPLIT 16   // j-splits; 512 cols per block
#define CHUNK 64    // cols per LDS-staged chunk
#define NCHUNK 8    // 512 / 64
#define NRB 32      // row-blocks of 256 rows

constexpr float INV_T = 14.285714285714286f;   // 1/0.07 (= subtracted row max M)
constexpr float EC1   = 20.609929155556620f;   // INV_T * log2(e)
constexpr float EC0   = -20.609929155556620f;  // -INV_T * log2(e)
constexpr float LN2   = 0.6931471805599453f;

typedef __attribute__((ext_vector_type(8))) short bf16x8;
typedef __attribute__((ext_vector_type(4))) float f32x4;

__device__ __forceinline__ float bf2f(ushort u) {
    union { unsigned int i; float f; } v; v.i = ((unsigned int)u) << 16; return v.f;
}

// ---- kernel 1: L2-normalize rows -> bf16 + selfdot; zero the output scalar ----
__global__ __launch_bounds__(256) void k_norm(const float* __restrict__ feat,
                                              ushort* __restrict__ fb,
                                              float* __restrict__ selfdot,
                                              float* __restrict__ out) {
    const int gid = blockIdx.x * 256 + threadIdx.x;
    if (gid == 0) out[0] = 0.0f;               // k_final atomicAdds into out
    const int r    = gid >> 6;                 // one wave per row
    const int lane = threadIdx.x & 63;
    const float2 v = ((const float2*)(feat + (size_t)r * DD))[lane];
    float ss = v.x * v.x + v.y * v.y;
#pragma unroll
    for (int off = 1; off < 64; off <<= 1) ss += __shfl_xor(ss, off, 64);
    const float scale = 1.0f / fmaxf(sqrtf(ss), 1e-12f);
    __hip_bfloat162 h2;
    h2.x = __float2bfloat16(v.x * scale);
    h2.y = __float2bfloat16(v.y * scale);
    ((__hip_bfloat162*)(fb + (size_t)r * DD))[lane] = h2;
    // self-dot of the QUANTIZED row (matches the MFMA diagonal)
    const float xb = bf2f(((ushort2*)&h2)->x), yb = bf2f(((ushort2*)&h2)->y);
    float s2 = xb * xb + yb * yb;
#pragma unroll
    for (int off = 1; off < 64; off <<= 1) s2 += __shfl_xor(s2, off, 64);
    if (lane == 0) selfdot[r] = s2;
}

// stage one 64-col chunk's B-fragments into LDS, fragment-major, 8 waves.
// Pair p = jt*4+kt (16 pairs); wave w stages pairs 2w and 2w+1.
// LDS dst = wave-uniform base + lane*16 (HW rule); per-lane GLOBAL address
// does the fragment gather.
__device__ __forceinline__ void stage_chunk(const ushort* __restrict__ fb, ushort* sbuf,
                                            int jb, int w, int n15, int q) {
#pragma unroll
    for (int h = 0; h < 2; ++h) {
        const int p = w * 2 + h;
        const ushort* g = fb + (size_t)(jb + (p >> 2) * 16 + n15) * DD + (p & 3) * 32 + q * 8;
        __builtin_amdgcn_global_load_lds(
            (const __attribute__((address_space(1))) void*)g,
            (__attribute__((address_space(3))) void*)(sbuf + p * 512),
            16, 0, 0);
    }
}

// ---- kernel 2: F*F^T, LDS double-buffered B, fused exp/pos/cnt epilogue ----
// Block: 256 rows x 512 cols, 8 waves of 32 rows (per-wave code == R5).
// Grid 512 = 32 rb x 16 js -> 2 blocks/CU, 16 waves/CU.
// Plain per-split stores; NO atomics, NO fences, NO in-kernel finalize (R8 lesson).
__global__ __launch_bounds__(512, 2) void k_main(const ushort* __restrict__ fb,
                                                 const int* __restrict__ labels,
                                                 float* __restrict__ g_se,
                                                 float* __restrict__ g_ps,
                                                 float* __restrict__ g_ct) {
    __shared__ ushort sB[2][CHUNK * DD];   // 2 x 16 KB, fragment-major
    __shared__ int slab[512];              // labels of this block's col range

    const int tid  = threadIdx.x;
    const int lane = tid & 63;
    const int w    = tid >> 6;                  // 0..7
    const int rb   = blockIdx.x >> 4;           // 0..31
    const int js   = blockIdx.x & (NSPLIT - 1); // 0..15
    const int i0   = rb * 256 + w * 32;
    const int jb0  = js * 512;
    const int q    = lane >> 4;
    const int n15  = lane & 15;

    slab[tid] = labels[(jb0 + tid) & (NB - 1)];

    // A fragments: 2 row-tiles x 4 kt (32 regs), resident whole kernel
    bf16x8 afrag[2][4];
#pragma unroll
    for (int tt = 0; tt < 2; ++tt) {
        const ushort* rp = fb + (size_t)(i0 + tt * 16 + n15) * DD + q * 8;
#pragma unroll
        for (int kt = 0; kt < 4; ++kt) afrag[tt][kt] = *(const bf16x8*)(rp + kt * 32);
    }
    // labels of this lane's 8 accumulator rows (C/D map: row = q*4+r)
    int labi[8];
#pragma unroll
    for (int tt = 0; tt < 2; ++tt)
#pragma unroll
        for (int r = 0; r < 4; ++r)
            labi[tt * 4 + r] = labels[(i0 + tt * 16 + q * 4 + r) & (NB - 1)];

    float a_se[8] = {}, a_ps[8] = {}, a_ct[8] = {};

    stage_chunk(fb, &sB[0][0], jb0, w, n15, q);
    __syncthreads();

    for (int c = 0; c < NCHUNK; ++c) {
        if (c + 1 < NCHUNK)
            stage_chunk(fb, &sB[(c + 1) & 1][0], jb0 + (c + 1) * CHUNK, w, n15, q);
        const ushort* sb = &sB[c & 1][0];
        const int crel = c * CHUNK;
#pragma unroll
        for (int jt = 0; jt < 4; ++jt) {
            bf16x8 bf[4];
#pragma unroll
            for (int kt = 0; kt < 4; ++kt)
                bf[kt] = *(const bf16x8*)(sb + (jt * 4 + kt) * 512 + lane * 8); // conflict-free
            const int labj = slab[crel + jt * 16 + n15];
            f32x4 a0 = {0.f, 0.f, 0.f, 0.f}, a1 = {0.f, 0.f, 0.f, 0.f};
#pragma unroll
            for (int kt = 0; kt < 4; ++kt) {
                a0 = __builtin_amdgcn_mfma_f32_16x16x32_bf16(afrag[0][kt], bf[kt], a0, 0, 0, 0);
                a1 = __builtin_amdgcn_mfma_f32_16x16x32_bf16(afrag[1][kt], bf[kt], a1, 0, 0, 0);
            }
#pragma unroll
            for (int r = 0; r < 4; ++r) {
                const float d0 = a0[r], d1 = a1[r];
                a_se[r]     += __builtin_amdgcn_exp2f(fmaf(d0, EC1, EC0));
                a_se[4 + r] += __builtin_amdgcn_exp2f(fmaf(d1, EC1, EC0));
                const bool m0 = (labi[r] == labj), m1 = (labi[4 + r] == labj);
                a_ps[r]     += m0 ? d0 : 0.0f;   // raw dot; scaled/shifted in k_final
                a_ps[4 + r] += m1 ? d1 : 0.0f;
                a_ct[r]     += m0 ? 1.0f : 0.0f;
                a_ct[4 + r] += m1 ? 1.0f : 0.0f;
            }
        }
        __syncthreads();
    }

    // 16 lanes per quad share the same rows; reduce, single plain store each
#pragma unroll
    for (int s = 0; s < 8; ++s) {
        float v1 = a_se[s], v2 = a_ps[s], v3 = a_ct[s];
#pragma unroll
        for (int off = 1; off < 16; off <<= 1) {
            v1 += __shfl_xor(v1, off, 64);
            v2 += __shfl_xor(v2, off, 64);
            v3 += __shfl_xor(v3, off, 64);
        }
        if (n15 == 0) {
            const int row = i0 + (s >> 2) * 16 + q * 4 + (s & 3);
            g_se[js * NN + row] = v1;
            g_ps[js * NN + row] = v2;
            g_ct[js * NN + row] = v3;
        }
    }
}

// ---- kernel 3: per-row loss (analytic self-term removal) -> atomic mean ----
__global__ __launch_bounds__(256) void k_final(const float* __restrict__ g_se,
                                               const float* __restrict__ g_ps,
                                               const float* __restrict__ g_ct,
                                               const float* __restrict__ selfdot,
                                               float* __restrict__ out) {
    const int r = blockIdx.x * 256 + threadIdx.x;
    float se = 0.f, ps = 0.f, ct = 0.f;
#pragma unroll
    for (int t = 0; t < NSPLIT; ++t) {
        se += g_se[t * NN + r];
        ps += g_ps[t * NN + r];
        ct += g_ct[t * NN + r];
    }
    const float sd = selfdot[r];
    se -= __builtin_amdgcn_exp2f(fmaf(sd, EC1, EC0));  // drop diagonal from sumexp
    ct -= 1.0f;                                        // drop diagonal from positives
    const float possum = INV_T * (ps - sd - ct);       // sum_pos (l_ij - M)
    const float lg  = __builtin_amdgcn_logf(se + 1e-12f) * LN2;
    const float mlpp = (possum - ct * lg) / fmaxf(ct, 1.0f);
    float v = -mlpp * (1.0f / (float)NN);
#pragma unroll
    for (int off = 1; off < 64; off <<= 1) v += __shfl_xor(v, off, 64);
    __shared__ float sred[4];
    if ((threadIdx.x & 63) == 0) sred[threadIdx.x >> 6] = v;
    __syncthreads();
    if (threadIdx.x == 0) atomicAdd(out, sred[0] + sred[1] + sred[2] + sred[3]);
}

extern "C" void kernel_launch(void* const* d_in, const int* in_sizes, int n_in,
                              void* d_out, int out_size, void* d_ws, size_t ws_size,
                              hipStream_t stream) {
    const float* feat = (const float*)d_in[0];
    const int* labels = (const int*)d_in[1];
    float* out        = (float*)d_out;
    char* ws          = (char*)d_ws;

    ushort* fb      = (ushort*)ws;                                   // 2 MB
    float* g_se     = (float*)(ws + (size_t)2 * 1024 * 1024);        // [16][NN]
    float* g_ps     = g_se + NSPLIT * NN;
    float* g_ct     = g_ps + NSPLIT * NN;
    float* selfdot  = g_ct + NSPLIT * NN;                            // NN f32

    k_norm<<<NN / 4, 256, 0, stream>>>(feat, fb, selfdot, out);
    k_main<<<NRB * NSPLIT, 512, 0, stream>>>(fb, labels, g_se, g_ps, g_ct);
    k_final<<<NN / 256, 256, 0, stream>>>(g_se, g_ps, g_ct, selfdot, out);
}